// Round 3
// baseline (100.770 us; speedup 1.0000x reference)
//
#include <hip/hip_runtime.h>
#include <math.h>

#define NTX_EPS 1e-8f

// Raw barrier that does NOT drain vmcnt: staged global loads stay in flight.
// lgkmcnt(0) makes this wave's ds_writes visible before the barrier.
__device__ __forceinline__ void block_sync_lds() {
    asm volatile("s_waitcnt lgkmcnt(0)" ::: "memory");
    __builtin_amdgcn_sched_barrier(0);
    __builtin_amdgcn_s_barrier();
    __builtin_amdgcn_sched_barrier(0);
}

// Kernel 1: one block per (batch, chunk-slot). 256 threads.
// slot 0..3 -> level0 (D=4096) d-range slot*1024
// slot 4..5 -> level1 (D=2048) d-range (slot-4)*1024
// slot 6    -> level2 (D=1024) full (finishes its loss in-kernel)
// Pipeline per 128-float chunk: write stg(c+1)->LDS[nxt] | issue loads(c+2)
// | compute(c) from LDS[cur] | lgkmcnt(0)+s_barrier (no vmcnt drain).
__global__ __launch_bounds__(256, 4)
void ntxent_partial(const float* __restrict__ ts0, const float* __restrict__ rs0,
                    const float* __restrict__ ts1, const float* __restrict__ rs1,
                    const float* __restrict__ ts2, const float* __restrict__ rs2,
                    float* __restrict__ ws, float* __restrict__ out)
{
    __shared__ float M[2][32][132];           // 33792 B, double buffer
    __shared__ float rn2[16];
    __shared__ float tnormS[16], rnormS[16];
    // Gp overlays M[0] (dead after the main loop): 4*16*36*4 = 9216 B
    float (*Gp)[16][36] = (float (*)[16][36])&M[0][0][0];

    const int bid  = blockIdx.x;
    const int b    = bid / 7;
    const int slot = bid % 7;

    const float* tp; const float* rp; int D; int chunk0;
    if (slot < 4)      { tp = ts0; rp = rs0; D = 4096; chunk0 = slot; }
    else if (slot < 6) { tp = ts1; rp = rs1; D = 2048; chunk0 = slot - 4; }
    else               { tp = ts2; rp = rs2; D = 1024; chunk0 = 0; }

    const int t    = threadIdx.x;
    const int half = t >> 7;                  // 0: ts rows, 1: rs rows
    const int lrow = (t >> 3) & 15;
    const int lc4  = t & 7;
    const float* gsrc = (half ? rp : tp) + (size_t)b * 16 * D + (size_t)lrow * D
                        + (size_t)chunk0 * 1024;

    const int tile = t & 7;
    const int s    = t >> 3;                  // d-slice 0..31
    const int ti   = tile >> 2;
    const int tj   = tile & 3;

    float acc[8][8];
#pragma unroll
    for (int i = 0; i < 8; ++i)
#pragma unroll
        for (int j = 0; j < 8; ++j) acc[i][j] = 0.f;

    float rsq = 0.f;
    float4 stg[4];

    // ---- prologue: chunk0 -> LDS[0]; chunk1 -> stg ----
#pragma unroll
    for (int it = 0; it < 4; ++it)
        stg[it] = *(const float4*)(gsrc + (lc4 + 8*it) * 4);
#pragma unroll
    for (int it = 0; it < 4; ++it)
        *(float4*)&M[0][half*16 + lrow][(lc4 + 8*it)*4] = stg[it];
    if (half) {
#pragma unroll
        for (int it = 0; it < 4; ++it)
            rsq += stg[it].x*stg[it].x + stg[it].y*stg[it].y
                 + stg[it].z*stg[it].z + stg[it].w*stg[it].w;
    }
#pragma unroll
    for (int it = 0; it < 4; ++it)
        stg[it] = *(const float4*)(gsrc + 128 + (lc4 + 8*it) * 4);
    block_sync_lds();

    // ---- main loop: 8 chunks of 128 floats ----
    for (int c = 0; c < 8; ++c) {
        const int cur = c & 1;
        const int nxt = cur ^ 1;
        if (c + 1 < 8) {
#pragma unroll
            for (int it = 0; it < 4; ++it)
                *(float4*)&M[nxt][half*16 + lrow][(lc4 + 8*it)*4] = stg[it];
            if (half) {
#pragma unroll
                for (int it = 0; it < 4; ++it)
                    rsq += stg[it].x*stg[it].x + stg[it].y*stg[it].y
                         + stg[it].z*stg[it].z + stg[it].w*stg[it].w;
            }
        }
        if (c + 2 < 8) {
#pragma unroll
            for (int it = 0; it < 4; ++it)
                stg[it] = *(const float4*)(gsrc + (size_t)(c+2)*128 + (lc4 + 8*it)*4);
        }
        // compute chunk c from M[cur]
        const float* Arow = &M[cur][ti*8][0] + 4*s;
        const float* Brow = &M[cur][tj*8][0] + 4*s;
        float av[8][4], bv[8][4];
#pragma unroll
        for (int r = 0; r < 8; ++r)
            *(float4*)av[r] = *(const float4*)(Arow + r*132);
#pragma unroll
        for (int r = 0; r < 8; ++r)
            *(float4*)bv[r] = *(const float4*)(Brow + r*132);
#pragma unroll
        for (int dd = 0; dd < 4; ++dd)
#pragma unroll
            for (int i = 0; i < 8; ++i)
#pragma unroll
                for (int j = 0; j < 8; ++j)
                    acc[i][j] = fmaf(av[i][dd], bv[j][dd], acc[i][j]);
        if (c + 1 < 8) block_sync_lds();
    }

    // ---- epilogue ----
    // reduce acc over the 8 d-slices within each wave (lane bits 3..5)
#pragma unroll
    for (int i = 0; i < 8; ++i)
#pragma unroll
        for (int j = 0; j < 8; ++j) {
            float v = acc[i][j];
            v += __shfl_xor(v, 8,  64);
            v += __shfl_xor(v, 16, 64);
            v += __shfl_xor(v, 32, 64);
            acc[i][j] = v;
        }

    rsq += __shfl_xor(rsq, 1, 64);
    rsq += __shfl_xor(rsq, 2, 64);
    rsq += __shfl_xor(rsq, 4, 64);
    if (half == 1 && (t & 7) == 0) rn2[lrow] = rsq;

    const int w = t >> 6;
    if ((t & 63) < 8) {
#pragma unroll
        for (int i = 0; i < 8; ++i)
#pragma unroll
            for (int j = 0; j < 8; ++j)
                Gp[w][ti*8 + i][tj*8 + j] = acc[i][j];
    }
    __syncthreads();

    float* slotp = ws + (size_t)(b * 6 + slot) * 544;
    for (int e = t; e < 512; e += 256) {
        int n = e >> 5, m = e & 31;
        float v = Gp[0][n][m] + Gp[1][n][m] + Gp[2][n][m] + Gp[3][n][m];
        if (slot == 6) Gp[0][n][m] = v;
        else           slotp[e] = v;
    }
    if (slot != 6) {
        if (t < 16) slotp[512 + t] = rn2[t];
        return;
    }

    // ---- slot 6 (level 2): finish loss here ----
    __syncthreads();
    if (t < 16) {
        tnormS[t] = fmaxf(sqrtf(Gp[0][t][t]), NTX_EPS);
        rnormS[t] = fmaxf(sqrtf(rn2[t]), NTX_EPS);
    }
    __syncthreads();

    float loss = 0.f;
    if (t < 16) {
        const int n = t;
        const float itn = 2.0f / tnormS[n];
        float lg[32];
#pragma unroll
        for (int m = 0; m < 16; ++m)
            lg[m] = Gp[0][n][16 + m] * itn / rnormS[m];
#pragma unroll
        for (int k = 0; k < 16; ++k)
            lg[16 + k] = Gp[0][n][k] * itn / tnormS[k];
        const float pos = lg[n];
        float mx = -3.4e38f;
#pragma unroll
        for (int m = 0; m < 32; ++m)
            mx = (m == 16 + n) ? mx : fmaxf(mx, lg[m]);
        float sm = 0.f;
#pragma unroll
        for (int m = 0; m < 32; ++m)
            sm += (m == 16 + n) ? 0.f : expf(lg[m] - mx);
        loss = logf(sm) + mx - pos;
    }
    loss += __shfl_xor(loss, 1, 64);
    loss += __shfl_xor(loss, 2, 64);
    loss += __shfl_xor(loss, 4, 64);
    loss += __shfl_xor(loss, 8, 64);
    if (t == 0) atomicAdd(out, loss * (1.0f / 512.0f));
}

// Kernel 2: sum partial Grams for levels 0/1 and do the logsumexp.
// grid = B*2 (b = bid>>1, lvl = bid&1), block = 64.
__global__ __launch_bounds__(64)
void ntxent_finish(const float* __restrict__ ws, float* __restrict__ out)
{
    __shared__ float G[16][33];
    __shared__ float rn2s[16];
    __shared__ float tn[16], rn[16];

    const int bid = blockIdx.x;
    const int b   = bid >> 1;
    const int lvl = bid & 1;
    const int base = b * 6 + (lvl ? 4 : 0);
    const int cnt  = lvl ? 2 : 4;
    const int l = threadIdx.x;

    for (int e = l; e < 512; e += 64) {
        float s = 0.f;
        for (int c = 0; c < cnt; ++c) s += ws[(size_t)(base + c) * 544 + e];
        G[e >> 5][e & 31] = s;
    }
    if (l < 16) {
        float s = 0.f;
        for (int c = 0; c < cnt; ++c) s += ws[(size_t)(base + c) * 544 + 512 + l];
        rn2s[l] = s;
    }
    __syncthreads();
    if (l < 16) {
        tn[l] = fmaxf(sqrtf(G[l][l]), NTX_EPS);
        rn[l] = fmaxf(sqrtf(rn2s[l]), NTX_EPS);
    }
    __syncthreads();

    float loss = 0.f;
    if (l < 16) {
        const int n = l;
        const float itn = 2.0f / tn[n];
        float lg[32];
#pragma unroll
        for (int m = 0; m < 16; ++m)
            lg[m] = G[n][16 + m] * itn / rn[m];
#pragma unroll
        for (int k = 0; k < 16; ++k)
            lg[16 + k] = G[n][k] * itn / tn[k];
        const float pos = lg[n];
        float mx = -3.4e38f;
#pragma unroll
        for (int m = 0; m < 32; ++m)
            mx = (m == 16 + n) ? mx : fmaxf(mx, lg[m]);
        float sm = 0.f;
#pragma unroll
        for (int m = 0; m < 32; ++m)
            sm += (m == 16 + n) ? 0.f : expf(lg[m] - mx);
        loss = logf(sm) + mx - pos;
    }
    loss += __shfl_xor(loss, 1, 64);
    loss += __shfl_xor(loss, 2, 64);
    loss += __shfl_xor(loss, 4, 64);
    loss += __shfl_xor(loss, 8, 64);
    if (l == 0) atomicAdd(out, loss * (1.0f / 512.0f));
}

extern "C" void kernel_launch(void* const* d_in, const int* in_sizes, int n_in,
                              void* d_out, int out_size, void* d_ws, size_t ws_size,
                              hipStream_t stream) {
    const float* ts0 = (const float*)d_in[0];
    const float* rs0 = (const float*)d_in[1];
    const float* ts1 = (const float*)d_in[2];
    const float* rs1 = (const float*)d_in[3];
    const float* ts2 = (const float*)d_in[4];
    const float* rs2 = (const float*)d_in[5];
    float* out = (float*)d_out;
    float* ws  = (float*)d_ws;

    hipMemsetAsync(out, 0, sizeof(float), stream);

    const int B = in_sizes[0] / (16 * 4096);   // 256
    hipLaunchKernelGGL(ntxent_partial, dim3(B * 7), dim3(256), 0, stream,
                       ts0, rs0, ts1, rs1, ts2, rs2, ws, out);
    hipLaunchKernelGGL(ntxent_finish, dim3(B * 2), dim3(64), 0, stream,
                       ws, out);
}

// Round 4
// 80.931 us; speedup vs baseline: 1.2451x; 1.2451x over previous
//
#include <hip/hip_runtime.h>
#include <math.h>

#define NTX_EPS 1e-8f

// Raw barrier that does NOT drain vmcnt: staged global loads stay in flight.
// lgkmcnt(0) makes this wave's ds_writes visible before the barrier.
__device__ __forceinline__ void block_sync_lds() {
    asm volatile("s_waitcnt lgkmcnt(0)" ::: "memory");
    __builtin_amdgcn_sched_barrier(0);
    __builtin_amdgcn_s_barrier();
    __builtin_amdgcn_sched_barrier(0);
}

// Kernel 1: one block per (batch, chunk-slot). 256 threads.
// slot 0..3 -> level0 (D=4096) d-range slot*1024
// slot 4..5 -> level1 (D=2048) d-range (slot-4)*1024
// slot 6    -> level2 (D=1024) full (finishes its loss in-kernel)
// Pipeline per 128-float chunk: write stg(c+1)->LDS[nxt] | issue loads(c+2)
// | compute(c) from LDS[cur] | lgkmcnt(0)+s_barrier (no vmcnt drain).
// NOTE: no min-waves hint — (256,4) forced 64 VGPR and spilled acc[8][8]
// to scratch (R3: WRITE_SIZE 3MB->64MB, dur +31%). LDS caps us at 4
// blocks/CU regardless, so <=128 VGPR is the right target, not 64.
__global__ __launch_bounds__(256)
void ntxent_partial(const float* __restrict__ ts0, const float* __restrict__ rs0,
                    const float* __restrict__ ts1, const float* __restrict__ rs1,
                    const float* __restrict__ ts2, const float* __restrict__ rs2,
                    float* __restrict__ ws, float* __restrict__ out)
{
    __shared__ float M[2][32][132];           // 33792 B, double buffer
    __shared__ float rn2[16];
    __shared__ float tnormS[16], rnormS[16];
    // Gp overlays M[0] (dead after the main loop): 4*16*36*4 = 9216 B
    float (*Gp)[16][36] = (float (*)[16][36])&M[0][0][0];

    const int bid  = blockIdx.x;
    const int b    = bid / 7;
    const int slot = bid % 7;

    const float* tp; const float* rp; int D; int chunk0;
    if (slot < 4)      { tp = ts0; rp = rs0; D = 4096; chunk0 = slot; }
    else if (slot < 6) { tp = ts1; rp = rs1; D = 2048; chunk0 = slot - 4; }
    else               { tp = ts2; rp = rs2; D = 1024; chunk0 = 0; }

    const int t    = threadIdx.x;
    const int half = t >> 7;                  // 0: ts rows, 1: rs rows
    const int lrow = (t >> 3) & 15;
    const int lc4  = t & 7;
    const float* gsrc = (half ? rp : tp) + (size_t)b * 16 * D + (size_t)lrow * D
                        + (size_t)chunk0 * 1024;

    const int tile = t & 7;
    const int s    = t >> 3;                  // d-slice 0..31
    const int ti   = tile >> 2;
    const int tj   = tile & 3;

    float acc[8][8];
#pragma unroll
    for (int i = 0; i < 8; ++i)
#pragma unroll
        for (int j = 0; j < 8; ++j) acc[i][j] = 0.f;

    float rsq = 0.f;
    float4 stg[4];

    // ---- prologue: chunk0 -> LDS[0]; chunk1 -> stg ----
#pragma unroll
    for (int it = 0; it < 4; ++it)
        stg[it] = *(const float4*)(gsrc + (lc4 + 8*it) * 4);
#pragma unroll
    for (int it = 0; it < 4; ++it)
        *(float4*)&M[0][half*16 + lrow][(lc4 + 8*it)*4] = stg[it];
    if (half) {
#pragma unroll
        for (int it = 0; it < 4; ++it)
            rsq += stg[it].x*stg[it].x + stg[it].y*stg[it].y
                 + stg[it].z*stg[it].z + stg[it].w*stg[it].w;
    }
#pragma unroll
    for (int it = 0; it < 4; ++it)
        stg[it] = *(const float4*)(gsrc + 128 + (lc4 + 8*it) * 4);
    block_sync_lds();

    // ---- main loop: 8 chunks of 128 floats ----
    for (int c = 0; c < 8; ++c) {
        const int cur = c & 1;
        const int nxt = cur ^ 1;
        if (c + 1 < 8) {
#pragma unroll
            for (int it = 0; it < 4; ++it)
                *(float4*)&M[nxt][half*16 + lrow][(lc4 + 8*it)*4] = stg[it];
            if (half) {
#pragma unroll
                for (int it = 0; it < 4; ++it)
                    rsq += stg[it].x*stg[it].x + stg[it].y*stg[it].y
                         + stg[it].z*stg[it].z + stg[it].w*stg[it].w;
            }
        }
        if (c + 2 < 8) {
#pragma unroll
            for (int it = 0; it < 4; ++it)
                stg[it] = *(const float4*)(gsrc + (size_t)(c+2)*128 + (lc4 + 8*it)*4);
        }
        // compute chunk c from M[cur]
        const float* Arow = &M[cur][ti*8][0] + 4*s;
        const float* Brow = &M[cur][tj*8][0] + 4*s;
        float av[8][4], bv[8][4];
#pragma unroll
        for (int r = 0; r < 8; ++r)
            *(float4*)av[r] = *(const float4*)(Arow + r*132);
#pragma unroll
        for (int r = 0; r < 8; ++r)
            *(float4*)bv[r] = *(const float4*)(Brow + r*132);
#pragma unroll
        for (int dd = 0; dd < 4; ++dd)
#pragma unroll
            for (int i = 0; i < 8; ++i)
#pragma unroll
                for (int j = 0; j < 8; ++j)
                    acc[i][j] = fmaf(av[i][dd], bv[j][dd], acc[i][j]);
        if (c + 1 < 8) block_sync_lds();
    }

    // ---- epilogue ----
    // reduce acc over the 8 d-slices within each wave (lane bits 3..5)
#pragma unroll
    for (int i = 0; i < 8; ++i)
#pragma unroll
        for (int j = 0; j < 8; ++j) {
            float v = acc[i][j];
            v += __shfl_xor(v, 8,  64);
            v += __shfl_xor(v, 16, 64);
            v += __shfl_xor(v, 32, 64);
            acc[i][j] = v;
        }

    rsq += __shfl_xor(rsq, 1, 64);
    rsq += __shfl_xor(rsq, 2, 64);
    rsq += __shfl_xor(rsq, 4, 64);
    if (half == 1 && (t & 7) == 0) rn2[lrow] = rsq;

    const int w = t >> 6;
    if ((t & 63) < 8) {
#pragma unroll
        for (int i = 0; i < 8; ++i)
#pragma unroll
            for (int j = 0; j < 8; ++j)
                Gp[w][ti*8 + i][tj*8 + j] = acc[i][j];
    }
    __syncthreads();

    float* slotp = ws + (size_t)(b * 6 + slot) * 544;
    for (int e = t; e < 512; e += 256) {
        int n = e >> 5, m = e & 31;
        float v = Gp[0][n][m] + Gp[1][n][m] + Gp[2][n][m] + Gp[3][n][m];
        if (slot == 6) Gp[0][n][m] = v;
        else           slotp[e] = v;
    }
    if (slot != 6) {
        if (t < 16) slotp[512 + t] = rn2[t];
        return;
    }

    // ---- slot 6 (level 2): finish loss here ----
    __syncthreads();
    if (t < 16) {
        tnormS[t] = fmaxf(sqrtf(Gp[0][t][t]), NTX_EPS);
        rnormS[t] = fmaxf(sqrtf(rn2[t]), NTX_EPS);
    }
    __syncthreads();

    float loss = 0.f;
    if (t < 16) {
        const int n = t;
        const float itn = 2.0f / tnormS[n];
        float lg[32];
#pragma unroll
        for (int m = 0; m < 16; ++m)
            lg[m] = Gp[0][n][16 + m] * itn / rnormS[m];
#pragma unroll
        for (int k = 0; k < 16; ++k)
            lg[16 + k] = Gp[0][n][k] * itn / tnormS[k];
        const float pos = lg[n];
        float mx = -3.4e38f;
#pragma unroll
        for (int m = 0; m < 32; ++m)
            mx = (m == 16 + n) ? mx : fmaxf(mx, lg[m]);
        float sm = 0.f;
#pragma unroll
        for (int m = 0; m < 32; ++m)
            sm += (m == 16 + n) ? 0.f : expf(lg[m] - mx);
        loss = logf(sm) + mx - pos;
    }
    loss += __shfl_xor(loss, 1, 64);
    loss += __shfl_xor(loss, 2, 64);
    loss += __shfl_xor(loss, 4, 64);
    loss += __shfl_xor(loss, 8, 64);
    if (t == 0) atomicAdd(out, loss * (1.0f / 512.0f));
}

// Kernel 2: sum partial Grams for levels 0/1 and do the logsumexp.
// grid = B*2 (b = bid>>1, lvl = bid&1), block = 64.
__global__ __launch_bounds__(64)
void ntxent_finish(const float* __restrict__ ws, float* __restrict__ out)
{
    __shared__ float G[16][33];
    __shared__ float rn2s[16];
    __shared__ float tn[16], rn[16];

    const int bid = blockIdx.x;
    const int b   = bid >> 1;
    const int lvl = bid & 1;
    const int base = b * 6 + (lvl ? 4 : 0);
    const int cnt  = lvl ? 2 : 4;
    const int l = threadIdx.x;

    for (int e = l; e < 512; e += 64) {
        float s = 0.f;
        for (int c = 0; c < cnt; ++c) s += ws[(size_t)(base + c) * 544 + e];
        G[e >> 5][e & 31] = s;
    }
    if (l < 16) {
        float s = 0.f;
        for (int c = 0; c < cnt; ++c) s += ws[(size_t)(base + c) * 544 + 512 + l];
        rn2s[l] = s;
    }
    __syncthreads();
    if (l < 16) {
        tn[l] = fmaxf(sqrtf(G[l][l]), NTX_EPS);
        rn[l] = fmaxf(sqrtf(rn2s[l]), NTX_EPS);
    }
    __syncthreads();

    float loss = 0.f;
    if (l < 16) {
        const int n = l;
        const float itn = 2.0f / tn[n];
        float lg[32];
#pragma unroll
        for (int m = 0; m < 16; ++m)
            lg[m] = G[n][16 + m] * itn / rn[m];
#pragma unroll
        for (int k = 0; k < 16; ++k)
            lg[16 + k] = G[n][k] * itn / tn[k];
        const float pos = lg[n];
        float mx = -3.4e38f;
#pragma unroll
        for (int m = 0; m < 32; ++m)
            mx = (m == 16 + n) ? mx : fmaxf(mx, lg[m]);
        float sm = 0.f;
#pragma unroll
        for (int m = 0; m < 32; ++m)
            sm += (m == 16 + n) ? 0.f : expf(lg[m] - mx);
        loss = logf(sm) + mx - pos;
    }
    loss += __shfl_xor(loss, 1, 64);
    loss += __shfl_xor(loss, 2, 64);
    loss += __shfl_xor(loss, 4, 64);
    loss += __shfl_xor(loss, 8, 64);
    if (l == 0) atomicAdd(out, loss * (1.0f / 512.0f));
}

extern "C" void kernel_launch(void* const* d_in, const int* in_sizes, int n_in,
                              void* d_out, int out_size, void* d_ws, size_t ws_size,
                              hipStream_t stream) {
    const float* ts0 = (const float*)d_in[0];
    const float* rs0 = (const float*)d_in[1];
    const float* ts1 = (const float*)d_in[2];
    const float* rs1 = (const float*)d_in[3];
    const float* ts2 = (const float*)d_in[4];
    const float* rs2 = (const float*)d_in[5];
    float* out = (float*)d_out;
    float* ws  = (float*)d_ws;

    hipMemsetAsync(out, 0, sizeof(float), stream);

    const int B = in_sizes[0] / (16 * 4096);   // 256
    hipLaunchKernelGGL(ntxent_partial, dim3(B * 7), dim3(256), 0, stream,
                       ts0, rs0, ts1, rs1, ts2, rs2, ws, out);
    hipLaunchKernelGGL(ntxent_finish, dim3(B * 2), dim3(64), 0, stream,
                       ws, out);
}

// Round 5
// 77.841 us; speedup vs baseline: 1.2946x; 1.0397x over previous
//
#include <hip/hip_runtime.h>
#include <math.h>

#define NTX_EPS 1e-8f

// Async global->LDS DMA, 16B per lane. LDS dst is wave-uniform base + lane*16.
__device__ __forceinline__ void async_load16(const float* g, float* lds) {
    __builtin_amdgcn_global_load_lds(
        (const __attribute__((address_space(1))) void*)g,
        (__attribute__((address_space(3))) void*)lds,
        16, 0, 0);
}

// Kernel 1: 1792 blocks x 128 threads. Block = (b, slot); each of the 2 waves
// independently handles a 512-float d-range (16 chunks of 32 floats), with a
// private triple-buffered LDS region and counted-vmcnt pipelining. NO
// __syncthreads in the main loop — waves are fully self-paced (R4 showed the
// barrier-locked structure idles 80% regardless of memory source).
// slot 0..3 -> level0 (D=4096), slot 4..5 -> level1 (D=2048), slot 6 -> level2.
// LDS chunk layout per buffer: [32 rows][32 floats], stride 128B = lane-linear
// for global_load_lds (row 8f+(l>>3), col (l&7)*4 == base + l*16B).
__global__ __launch_bounds__(128)
void ntxent_partial(const float* __restrict__ ts0, const float* __restrict__ rs0,
                    const float* __restrict__ ts1, const float* __restrict__ rs1,
                    const float* __restrict__ ts2, const float* __restrict__ rs2,
                    float* __restrict__ ws, float* __restrict__ out)
{
    __shared__ float Mbuf[2][3072];   // per-wave: 3 x 1024-float buffers

    const int bid  = blockIdx.x;
    const int b    = bid / 7;
    const int slot = bid % 7;

    const float* tp; const float* rp; int D; int chunk0;
    if (slot < 4)      { tp = ts0; rp = rs0; D = 4096; chunk0 = slot; }
    else if (slot < 6) { tp = ts1; rp = rs1; D = 2048; chunk0 = slot - 4; }
    else               { tp = ts2; rp = rs2; D = 1024; chunk0 = 0; }

    const int t = threadIdx.x;
    const int w = t >> 6;             // wave 0/1
    const int l = t & 63;

    const size_t dbase = (size_t)chunk0 * 1024 + (size_t)w * 512;
    const float* tbase = tp + (size_t)b * 16 * D + dbase;
    const float* rbase = rp + (size_t)b * 16 * D + dbase;

    const int lr = l >> 3;            // load row-within-8 (== d-slice s)
    const int lc = (l & 7) * 4;       // load float col

    float* myLDS = &Mbuf[w][0];

    const int s  = l >> 3;            // d-slice 0..7
    const int ti = (l & 7) >> 2;      // 0..1 -> output rows ti*8..+7
    const int tj = l & 3;             // 0..3 -> output cols tj*8..+7
    const int rrow = 16 + (l >> 2);   // rs row (LDS row 16..31) for norm acc
    const int rc   = (l & 3) * 8;     // first of two f4 cols for norm acc

    // Issue the 4 DMA loads (4 KB) for chunk c into buffer c%3.
    auto issue = [&](int c) {
        float* d = myLDS + (c % 3) * 1024;
        const float* g0 = tbase + (size_t)lr * D + c * 32 + lc;
        const float* g1 = rbase + (size_t)lr * D + c * 32 + lc;
        async_load16(g0, d);                       // ts rows 0..7
        async_load16(g0 + (size_t)8 * D, d + 256); // ts rows 8..15
        async_load16(g1, d + 512);                 // rs rows 0..7  (LDS 16..23)
        async_load16(g1 + (size_t)8 * D, d + 768); // rs rows 8..15 (LDS 24..31)
    };

    float acc[8][8];
#pragma unroll
    for (int i = 0; i < 8; ++i)
#pragma unroll
        for (int j = 0; j < 8; ++j) acc[i][j] = 0.f;
    float rsq = 0.f;

    auto compute_chunk = [&](const float* base) {
        float4 av[8], bv[8];
#pragma unroll
        for (int r = 0; r < 8; ++r)
            av[r] = *(const float4*)(base + (ti * 8 + r) * 32 + s * 4);
#pragma unroll
        for (int r = 0; r < 8; ++r)
            bv[r] = *(const float4*)(base + (tj * 8 + r) * 32 + s * 4);
        float4 q0 = *(const float4*)(base + rrow * 32 + rc);
        float4 q1 = *(const float4*)(base + rrow * 32 + rc + 4);
        rsq += q0.x*q0.x + q0.y*q0.y + q0.z*q0.z + q0.w*q0.w
             + q1.x*q1.x + q1.y*q1.y + q1.z*q1.z + q1.w*q1.w;
        const float* avf = (const float*)av;
        const float* bvf = (const float*)bv;
#pragma unroll
        for (int dd = 0; dd < 4; ++dd)
#pragma unroll
            for (int i = 0; i < 8; ++i)
#pragma unroll
                for (int j = 0; j < 8; ++j)
                    acc[i][j] = fmaf(avf[i*4+dd], bvf[j*4+dd], acc[i][j]);
    };

    // ---- pipelined main loop: 16 chunks, depth-2 prefetch, no barriers ----
    issue(0);
    issue(1);
    for (int c = 0; c < 14; ++c) {
        issue(c + 2);
        asm volatile("s_waitcnt vmcnt(8)" ::: "memory");  // chunk c landed
        __builtin_amdgcn_sched_barrier(0);
        compute_chunk(myLDS + (c % 3) * 1024);
    }
    asm volatile("s_waitcnt vmcnt(4)" ::: "memory");
    __builtin_amdgcn_sched_barrier(0);
    compute_chunk(myLDS + (14 % 3) * 1024);
    asm volatile("s_waitcnt vmcnt(0)" ::: "memory");
    __builtin_amdgcn_sched_barrier(0);
    compute_chunk(myLDS + (15 % 3) * 1024);

    // ---- epilogue ----
    // reduce acc over the 8 d-slices (lane bits 3..5)
#pragma unroll
    for (int i = 0; i < 8; ++i)
#pragma unroll
        for (int j = 0; j < 8; ++j) {
            float v = acc[i][j];
            v += __shfl_xor(v, 8, 64);
            v += __shfl_xor(v, 16, 64);
            v += __shfl_xor(v, 32, 64);
            acc[i][j] = v;
        }
    // rs row norms: 4 lanes per row (lane bits 0..1)
    rsq += __shfl_xor(rsq, 1, 64);
    rsq += __shfl_xor(rsq, 2, 64);

    __syncthreads();   // both waves done computing; buffers become scratch
    // this wave's region: [0..511] partial G (16x32), [512..527] partial rn2
    if (l < 8) {
#pragma unroll
        for (int i = 0; i < 8; ++i)
#pragma unroll
            for (int j = 0; j < 8; ++j)
                myLDS[(ti * 8 + i) * 32 + (tj * 8 + j)] = acc[i][j];
    }
    if ((l & 3) == 0) myLDS[512 + (l >> 2)] = rsq;
    __syncthreads();

    float* G0 = &Mbuf[0][0];
    float* G1 = &Mbuf[1][0];
    if (slot != 6) {
        float* slotp = ws + (size_t)(b * 6 + slot) * 544;
        for (int e = t; e < 512; e += 128) slotp[e] = G0[e] + G1[e];
        if (t < 16) slotp[512 + t] = G0[512 + t] + G1[512 + t];
        return;
    }

    // ---- slot 6 (level 2): finish loss in-kernel ----
    float* Gc   = G0 + 1088;   // combined 16x32 (buffer1 region, dead)
    float* rn2c = G0 + 1600;
    float* tnS  = G0 + 1616;
    float* rnS  = G0 + 1632;
    for (int e = t; e < 512; e += 128) Gc[e] = G0[e] + G1[e];
    if (t < 16) rn2c[t] = G0[512 + t] + G1[512 + t];
    __syncthreads();
    if (t < 16) {
        tnS[t] = fmaxf(sqrtf(Gc[t * 32 + t]), NTX_EPS);
        rnS[t] = fmaxf(sqrtf(rn2c[t]), NTX_EPS);
    }
    __syncthreads();

    float loss = 0.f;
    if (t < 16) {
        const int n = t;
        const float itn = 2.0f / tnS[n];   // includes 1/temperature
        float lg[32];
#pragma unroll
        for (int m = 0; m < 16; ++m)
            lg[m] = Gc[n * 32 + 16 + m] * itn / rnS[m];   // s_tr row
#pragma unroll
        for (int k = 0; k < 16; ++k)
            lg[16 + k] = Gc[n * 32 + k] * itn / tnS[k];   // s_tt row
        const float pos = lg[n];
        float mx = -3.4e38f;
#pragma unroll
        for (int m = 0; m < 32; ++m)
            mx = (m == 16 + n) ? mx : fmaxf(mx, lg[m]);   // exclude tt diag
        float sm = 0.f;
#pragma unroll
        for (int m = 0; m < 32; ++m)
            sm += (m == 16 + n) ? 0.f : expf(lg[m] - mx);
        loss = logf(sm) + mx - pos;
    }
    loss += __shfl_xor(loss, 1, 64);
    loss += __shfl_xor(loss, 2, 64);
    loss += __shfl_xor(loss, 4, 64);
    loss += __shfl_xor(loss, 8, 64);
    if (t == 0) atomicAdd(out, loss * (1.0f / 512.0f));
}

// Kernel 2: sum partial Grams for levels 0/1 and do the logsumexp.
// grid = B*2 (b = bid>>1, lvl = bid&1), block = 64.
__global__ __launch_bounds__(64)
void ntxent_finish(const float* __restrict__ ws, float* __restrict__ out)
{
    __shared__ float G[16][33];
    __shared__ float rn2s[16];
    __shared__ float tn[16], rn[16];

    const int bid = blockIdx.x;
    const int b   = bid >> 1;
    const int lvl = bid & 1;
    const int base = b * 6 + (lvl ? 4 : 0);
    const int cnt  = lvl ? 2 : 4;
    const int l = threadIdx.x;

    for (int e = l; e < 512; e += 64) {
        float s = 0.f;
        for (int c = 0; c < cnt; ++c) s += ws[(size_t)(base + c) * 544 + e];
        G[e >> 5][e & 31] = s;
    }
    if (l < 16) {
        float s = 0.f;
        for (int c = 0; c < cnt; ++c) s += ws[(size_t)(base + c) * 544 + 512 + l];
        rn2s[l] = s;
    }
    __syncthreads();
    if (l < 16) {
        tn[l] = fmaxf(sqrtf(G[l][l]), NTX_EPS);
        rn[l] = fmaxf(sqrtf(rn2s[l]), NTX_EPS);
    }
    __syncthreads();

    float loss = 0.f;
    if (l < 16) {
        const int n = l;
        const float itn = 2.0f / tn[n];
        float lg[32];
#pragma unroll
        for (int m = 0; m < 16; ++m)
            lg[m] = G[n][16 + m] * itn / rn[m];
#pragma unroll
        for (int k = 0; k < 16; ++k)
            lg[16 + k] = G[n][k] * itn / tn[k];
        const float pos = lg[n];
        float mx = -3.4e38f;
#pragma unroll
        for (int m = 0; m < 32; ++m)
            mx = (m == 16 + n) ? mx : fmaxf(mx, lg[m]);
        float sm = 0.f;
#pragma unroll
        for (int m = 0; m < 32; ++m)
            sm += (m == 16 + n) ? 0.f : expf(lg[m] - mx);
        loss = logf(sm) + mx - pos;
    }
    loss += __shfl_xor(loss, 1, 64);
    loss += __shfl_xor(loss, 2, 64);
    loss += __shfl_xor(loss, 4, 64);
    loss += __shfl_xor(loss, 8, 64);
    if (l == 0) atomicAdd(out, loss * (1.0f / 512.0f));
}

extern "C" void kernel_launch(void* const* d_in, const int* in_sizes, int n_in,
                              void* d_out, int out_size, void* d_ws, size_t ws_size,
                              hipStream_t stream) {
    const float* ts0 = (const float*)d_in[0];
    const float* rs0 = (const float*)d_in[1];
    const float* ts1 = (const float*)d_in[2];
    const float* rs1 = (const float*)d_in[3];
    const float* ts2 = (const float*)d_in[4];
    const float* rs2 = (const float*)d_in[5];
    float* out = (float*)d_out;
    float* ws  = (float*)d_ws;

    hipMemsetAsync(out, 0, sizeof(float), stream);

    const int B = in_sizes[0] / (16 * 4096);   // 256
    hipLaunchKernelGGL(ntxent_partial, dim3(B * 7), dim3(128), 0, stream,
                       ts0, rs0, ts1, rs1, ts2, rs2, ws, out);
    hipLaunchKernelGGL(ntxent_finish, dim3(B * 2), dim3(64), 0, stream,
                       ws, out);
}

// Round 7
// 65.801 us; speedup vs baseline: 1.5314x; 1.1830x over previous
//
#include <hip/hip_runtime.h>
#include <math.h>

#define NTX_EPS 1e-8f

typedef __fp16 half8 __attribute__((ext_vector_type(8)));
typedef __fp16 half2v __attribute__((ext_vector_type(2)));
typedef float f32x4 __attribute__((ext_vector_type(4)));

union H8 { half8 v8; half2v v2[4]; };

__device__ __forceinline__ half8 pack8(const float4& a, const float4& b) {
    H8 u;
    u.v2[0] = __builtin_amdgcn_cvt_pkrtz(a.x, a.y);
    u.v2[1] = __builtin_amdgcn_cvt_pkrtz(a.z, a.w);
    u.v2[2] = __builtin_amdgcn_cvt_pkrtz(b.x, b.y);
    u.v2[3] = __builtin_amdgcn_cvt_pkrtz(b.z, b.w);
    return u.v8;
}

// Kernel 1: 1792 blocks x 64 threads (ONE wave per block = one unit).
// Unit = (b, slot): slot 0..3 -> lvl0 d-range slot*1024; 4..5 -> lvl1; 6 -> lvl2.
// Register-only MFMA Gram: per K=32 step, lane l loads ts[l&15][kb+(l>>4)*8..+7]
// and rs likewise (2 float4 each, 16 rows x 128B fully-coalesced per step),
// packs to f16, then mfma(t,t)->tt, mfma(t,r)->tr, mfma(r,r)->rr (norms).
// A-frag and B-frag layouts are identical on lane index, so one register pair
// serves both operands; any k-permutation cancels in the Gram.
// NO LDS / barriers / shuffles in the hot loop (R1-R5: LDS-fed scalar-FMA
// structure was stuck at 85-100us regardless of sync scheme).
__global__ __launch_bounds__(64)
void ntxent_partial(const float* __restrict__ ts0, const float* __restrict__ rs0,
                    const float* __restrict__ ts1, const float* __restrict__ rs1,
                    const float* __restrict__ ts2, const float* __restrict__ rs2,
                    float* __restrict__ ws, float* __restrict__ out)
{
    __shared__ float Gs[16][33];
    __shared__ float rn2[16];
    __shared__ float tnS[16], rnS[16];

    const int bid  = blockIdx.x;
    const int b    = bid / 7;
    const int slot = bid % 7;

    const float* tp; const float* rp; int D; int chunk0;
    if (slot < 4)      { tp = ts0; rp = rs0; D = 4096; chunk0 = slot; }
    else if (slot < 6) { tp = ts1; rp = rs1; D = 2048; chunk0 = slot - 4; }
    else               { tp = ts2; rp = rs2; D = 1024; chunk0 = 0; }

    const int l   = threadIdx.x;
    const int row = l & 15;       // A-row / B-col index this lane feeds
    const int kg  = l >> 4;       // 0..3 k-group

    const size_t rbase = (size_t)b * 16 * D + (size_t)row * D
                       + (size_t)chunk0 * 1024 + (size_t)kg * 8;
    const float* tsrc = tp + rbase;
    const float* rsrc = rp + rbase;

    f32x4 acc_tt = {0.f, 0.f, 0.f, 0.f};
    f32x4 acc_tr = {0.f, 0.f, 0.f, 0.f};
    f32x4 acc_rr = {0.f, 0.f, 0.f, 0.f};

    // depth-1 register staging, manual ping-pong (static names only)
    float4 ta = *(const float4*)(tsrc);
    float4 tb = *(const float4*)(tsrc + 4);
    float4 ra = *(const float4*)(rsrc);
    float4 rb = *(const float4*)(rsrc + 4);

#pragma unroll 2
    for (int s = 0; s < 32; ++s) {        // 32 K-steps of 32 (1024 floats)
        float4 nta, ntb, nra, nrb;
        if (s + 1 < 32) {
            const float* tn = tsrc + (size_t)(s + 1) * 32;
            const float* rn = rsrc + (size_t)(s + 1) * 32;
            nta = *(const float4*)(tn);
            ntb = *(const float4*)(tn + 4);
            nra = *(const float4*)(rn);
            nrb = *(const float4*)(rn + 4);
        }
        half8 tf = pack8(ta, tb);
        half8 rf = pack8(ra, rb);
        acc_tt = __builtin_amdgcn_mfma_f32_16x16x32_f16(tf, tf, acc_tt, 0, 0, 0);
        acc_tr = __builtin_amdgcn_mfma_f32_16x16x32_f16(tf, rf, acc_tr, 0, 0, 0);
        acc_rr = __builtin_amdgcn_mfma_f32_16x16x32_f16(rf, rf, acc_rr, 0, 0, 0);
        ta = nta; tb = ntb; ra = nra; rb = nrb;
    }

    // C/D layout (m89-verified, dtype-independent): col = l&15, row = kg*4+r.
    const int m = row;                    // output column this lane holds
    if (slot != 6) {
        float* slotp = ws + (size_t)(b * 6 + slot) * 528;
#pragma unroll
        for (int r = 0; r < 4; ++r) {
            const int n = kg * 4 + r;
            slotp[n * 32 + m]      = acc_tt[r];
            slotp[n * 32 + 16 + m] = acc_tr[r];
        }
        if ((m >> 2) == kg) slotp[512 + m] = acc_rr[m & 3];  // rr diagonal
        return;
    }

    // ---- slot 6 (level 2): finish the loss in-kernel ----
#pragma unroll
    for (int r = 0; r < 4; ++r) {
        const int n = kg * 4 + r;
        Gs[n][m]      = acc_tt[r];
        Gs[n][16 + m] = acc_tr[r];
    }
    if ((m >> 2) == kg) rn2[m] = acc_rr[m & 3];
    __syncthreads();

    if (l < 16) {
        tnS[l] = fmaxf(sqrtf(Gs[l][l]), NTX_EPS);
        rnS[l] = fmaxf(sqrtf(rn2[l]), NTX_EPS);
    }
    __syncthreads();

    float loss = 0.f;
    if (l < 16) {
        const int n = l;
        const float itn = 2.0f / tnS[n];        // includes 1/temperature
        float lg[32];
#pragma unroll
        for (int j = 0; j < 16; ++j)
            lg[j] = Gs[n][16 + j] * itn / rnS[j];     // s_tr row
#pragma unroll
        for (int k = 0; k < 16; ++k)
            lg[16 + k] = Gs[n][k] * itn / tnS[k];     // s_tt row
        const float pos = lg[n];
        float mx = -3.4e38f;
#pragma unroll
        for (int j = 0; j < 32; ++j)
            mx = (j == 16 + n) ? mx : fmaxf(mx, lg[j]);   // exclude tt diag
        float sm = 0.f;
#pragma unroll
        for (int j = 0; j < 32; ++j)
            sm += (j == 16 + n) ? 0.f : expf(lg[j] - mx);
        loss = logf(sm) + mx - pos;
    }
    loss += __shfl_xor(loss, 1, 64);
    loss += __shfl_xor(loss, 2, 64);
    loss += __shfl_xor(loss, 4, 64);
    loss += __shfl_xor(loss, 8, 64);
    if (l == 0) atomicAdd(out, loss * (1.0f / 512.0f));
}

// Kernel 2: sum partial Grams for levels 0/1 and do the logsumexp.
// grid = B*2 (b = bid>>1, lvl = bid&1), block = 64.
__global__ __launch_bounds__(64)
void ntxent_finish(const float* __restrict__ ws, float* __restrict__ out)
{
    __shared__ float G[16][33];
    __shared__ float rn2s[16];
    __shared__ float tn[16], rn[16];

    const int bid = blockIdx.x;
    const int b   = bid >> 1;
    const int lvl = bid & 1;
    const int base = b * 6 + (lvl ? 4 : 0);
    const int cnt  = lvl ? 2 : 4;
    const int l = threadIdx.x;

    for (int e = l; e < 512; e += 64) {
        float s = 0.f;
        for (int c = 0; c < cnt; ++c) s += ws[(size_t)(base + c) * 528 + e];
        G[e >> 5][e & 31] = s;
    }
    if (l < 16) {
        float s = 0.f;
        for (int c = 0; c < cnt; ++c) s += ws[(size_t)(base + c) * 528 + 512 + l];
        rn2s[l] = s;
    }
    __syncthreads();
    if (l < 16) {
        tn[l] = fmaxf(sqrtf(G[l][l]), NTX_EPS);
        rn[l] = fmaxf(sqrtf(rn2s[l]), NTX_EPS);
    }
    __syncthreads();

    float loss = 0.f;
    if (l < 16) {
        const int n = l;
        const float itn = 2.0f / tn[n];
        float lg[32];
#pragma unroll
        for (int j = 0; j < 16; ++j)
            lg[j] = G[n][16 + j] * itn / rn[j];
#pragma unroll
        for (int k = 0; k < 16; ++k)
            lg[16 + k] = G[n][k] * itn / tn[k];
        const float pos = lg[n];
        float mx = -3.4e38f;
#pragma unroll
        for (int j = 0; j < 32; ++j)
            mx = (j == 16 + n) ? mx : fmaxf(mx, lg[j]);
        float sm = 0.f;
#pragma unroll
        for (int j = 0; j < 32; ++j)
            sm += (j == 16 + n) ? 0.f : expf(lg[j] - mx);
        loss = logf(sm) + mx - pos;
    }
    loss += __shfl_xor(loss, 1, 64);
    loss += __shfl_xor(loss, 2, 64);
    loss += __shfl_xor(loss, 4, 64);
    loss += __shfl_xor(loss, 8, 64);
    if (l == 0) atomicAdd(out, loss * (1.0f / 512.0f));
}

extern "C" void kernel_launch(void* const* d_in, const int* in_sizes, int n_in,
                              void* d_out, int out_size, void* d_ws, size_t ws_size,
                              hipStream_t stream) {
    const float* ts0 = (const float*)d_in[0];
    const float* rs0 = (const float*)d_in[1];
    const float* ts1 = (const float*)d_in[2];
    const float* rs1 = (const float*)d_in[3];
    const float* ts2 = (const float*)d_in[4];
    const float* rs2 = (const float*)d_in[5];
    float* out = (float*)d_out;
    float* ws  = (float*)d_ws;

    hipMemsetAsync(out, 0, sizeof(float), stream);

    const int B = in_sizes[0] / (16 * 4096);   // 256
    hipLaunchKernelGGL(ntxent_partial, dim3(B * 7), dim3(64), 0, stream,
                       ts0, rs0, ts1, rs1, ts2, rs2, ws, out);
    hipLaunchKernelGGL(ntxent_finish, dim3(B * 2), dim3(64), 0, stream,
                       ws, out);
}